// Round 1
// baseline (613.028 us; speedup 1.0000x reference)
//
#include <hip/hip_runtime.h>
#include <stdint.h>

#define B_SZ 4096
#define OBS 256
#define ACT 64
#define HID 1024
#define NOPT 8
#define DIN 328
#define DPAD 384
#define MAXTILES 40

typedef __attribute__((ext_vector_type(8))) short short8;
typedef __attribute__((ext_vector_type(4))) float floatx4;

__device__ __forceinline__ unsigned short f2bf(float x){
  union { float f; unsigned u; } v; v.f = x;
  unsigned r = v.u + 0x7fffu + ((v.u >> 16) & 1u);
  return (unsigned short)(r >> 16);
}
__device__ __forceinline__ float bf2f(unsigned short h){
  union { float f; unsigned u; } v; v.u = ((unsigned)h) << 16; return v.f;
}

__device__ __forceinline__ void load16(const void* g, void* l){
  __builtin_amdgcn_global_load_lds((const __attribute__((address_space(1))) void*)g,
                                   (__attribute__((address_space(3))) void*)l, 16, 0, 0);
}

// ---------------- transpose fp32 [K,N] -> bf16 [N,Kpad], zero-pad k>=K ----------------
__global__ void k_transpose(const float* __restrict__ W, unsigned short* __restrict__ WT,
                            int K, int N, int Kpad, long long wstride, long long tstride){
  __shared__ float tile[32][33];
  int k0 = blockIdx.x*32, n0 = blockIdx.y*32;
  const float* Wz = W + (long long)blockIdx.z * wstride;
  unsigned short* Tz = WT + (long long)blockIdx.z * tstride;
  int tx = threadIdx.x, ty = threadIdx.y; // 32 x 8
  #pragma unroll
  for (int i=0;i<4;i++){
    int k = k0 + ty + i*8;
    tile[ty+i*8][tx] = (k < K) ? Wz[(long long)k*N + n0 + tx] : 0.f;
  }
  __syncthreads();
  #pragma unroll
  for (int i=0;i<4;i++){
    int n = n0 + ty + i*8;
    Tz[(long long)n*Kpad + k0 + tx] = f2bf(tile[tx][ty+i*8]);
  }
}

// ---------------- option routing: counts, perm, tile table ----------------
__global__ void k_route(const int* __restrict__ option, int* __restrict__ perm,
                        int* __restrict__ optg, int4* __restrict__ table,
                        float* __restrict__ out){
  __shared__ int cnt[NOPT]; __shared__ int off[NOPT+1]; __shared__ int cur[NOPT];
  int tid = threadIdx.x;
  if (tid < NOPT) cnt[tid] = 0;
  __syncthreads();
  for (int b = tid; b < B_SZ; b += 256) atomicAdd(&cnt[option[b]], 1);
  __syncthreads();
  if (tid == 0){
    off[0] = 0;
    for (int o=0;o<NOPT;o++) off[o+1] = off[o] + cnt[o];
    for (int o=0;o<NOPT;o++) cur[o] = off[o];
    out[0] = 0.f; out[1] = 0.f;
  }
  __syncthreads();
  for (int b = tid; b < B_SZ; b += 256){
    int o = option[b];
    int pos = atomicAdd(&cur[o], 1);
    perm[pos] = b; optg[pos] = o;
  }
  __syncthreads();
  if (tid == 0){
    int idx = 0;
    for (int o=0;o<NOPT;o++){
      for (int t=0; t*128 < cnt[o]; t++){
        int4 e; e.x = off[o] + t*128; e.y = off[o+1]; e.z = o; e.w = 0;
        table[idx++] = e;
      }
    }
    for (; idx < MAXTILES; idx++){ int4 e; e.x=-1; e.y=0; e.z=0; e.w=0; table[idx]=e; }
  }
}

// ---------------- gather state/next_state rows by perm -> bf16, pad rows zero ----------------
__global__ void k_gather(const float* __restrict__ state, const float* __restrict__ ns,
                         const int* __restrict__ perm,
                         unsigned short* __restrict__ agS, unsigned short* __restrict__ agN){
  int i = blockIdx.x; int c = threadIdx.x; // 256
  long long o = (long long)i*OBS + c;
  if (i < B_SZ){
    long long src = (long long)perm[i]*OBS + c;
    agS[o] = f2bf(state[src]); agN[o] = f2bf(ns[src]);
  } else { agS[o] = 0; agN[o] = 0; }
}

// ---------------- build xq = [state, action, onehot, pad] bf16 [B, DPAD] ----------------
__global__ void k_xq(const float* __restrict__ state, const float* __restrict__ action,
                     const int* __restrict__ option, unsigned short* __restrict__ xq){
  int b = blockIdx.x; int c = threadIdx.x; // 384
  float v;
  if (c < OBS) v = state[(long long)b*OBS + c];
  else if (c < OBS+ACT) v = action[(long long)b*ACT + (c-OBS)];
  else if (c < OBS+ACT+NOPT) v = (option[b] == (c-OBS-ACT)) ? 1.f : 0.f;
  else v = 0.f;
  xq[(long long)b*DPAD + c] = f2bf(v);
}

// ---------------- fp32 -> bf16 convert ----------------
__global__ void k_cvt(const float* __restrict__ x, unsigned short* __restrict__ y, long long n){
  long long i = (long long)blockIdx.x*blockDim.x + threadIdx.x;
  if (i < n) y[i] = f2bf(x[i]);
}

// ---------------- bf16 GEMM: C[M,N] = act(A[M,K] * WT[N,K]^T + bias) ----------------
// dense: grid (N/128, M/128, Z). grouped: grid (N/128, MAXTILES), table-driven.
__global__ __launch_bounds__(256)
void k_gemm(const unsigned short* __restrict__ A, long long strideAz,
            const unsigned short* __restrict__ WT, long long strideWz,
            const float* __restrict__ bias, int biasStride,
            void* __restrict__ C, long long strideCz,
            int M, int N, int K, int relu, int outBf16,
            const int4* __restrict__ table)
{
  __shared__ unsigned short As[128*32];
  __shared__ unsigned short Bs[128*32];
  int m_start, m_end, z;
  if (table){
    int4 e = table[blockIdx.y];
    if (e.x < 0) return;
    m_start = e.x; m_end = e.y; z = e.z;
  } else {
    m_start = blockIdx.y * 128; m_end = M; z = blockIdx.z;
  }
  const unsigned short* Az = A + (long long)z*strideAz + (long long)m_start*K;
  const unsigned short* Wz = WT + (long long)z*strideWz;
  const float* bz = bias ? (bias + (long long)z*biasStride) : nullptr;
  int n0 = blockIdx.x * 128;

  int tid = threadIdx.x;
  int wave = tid >> 6, lane = tid & 63;
  int wm = wave & 1, wn = wave >> 1;
  int quad = lane >> 4, l16 = lane & 15;

  const floatx4 fzero = {0.f, 0.f, 0.f, 0.f};
  floatx4 acc[4][4];
  #pragma unroll
  for (int mi=0; mi<4; mi++)
    #pragma unroll
    for (int ni=0; ni<4; ni++)
      acc[mi][ni] = fzero;

  const char* Abase = (const char*)Az;
  const char* Bbase = (const char*)(Wz + (long long)n0*K);
  long long rowBytes = (long long)K*2;

  int c0 = tid, row0 = c0 >> 2, kc0 = c0 & 3;
  int c1 = tid + 256, row1 = c1 >> 2, kc1 = c1 & 3;
  char* lpA0 = ((char*)As) + wave*1024;
  char* lpA1 = ((char*)As) + 4096 + wave*1024;
  char* lpB0 = ((char*)Bs) + wave*1024;
  char* lpB1 = ((char*)Bs) + 4096 + wave*1024;

  int nkb = K >> 5;
  for (int kb = 0; kb < nkb; kb++){
    long long kbase = (long long)kb*64;
    load16(Abase + (long long)row0*rowBytes + kbase + kc0*16, lpA0);
    load16(Abase + (long long)row1*rowBytes + kbase + kc1*16, lpA1);
    load16(Bbase + (long long)row0*rowBytes + kbase + kc0*16, lpB0);
    load16(Bbase + (long long)row1*rowBytes + kbase + kc1*16, lpB1);
    __syncthreads();
    short8 af[4], bfr[4];
    #pragma unroll
    for (int mi=0; mi<4; mi++)
      af[mi] = *(const short8*)(As + (wm*64 + mi*16 + l16)*32 + quad*8);
    #pragma unroll
    for (int ni=0; ni<4; ni++)
      bfr[ni] = *(const short8*)(Bs + (wn*64 + ni*16 + l16)*32 + quad*8);
    #pragma unroll
    for (int mi=0; mi<4; mi++)
      #pragma unroll
      for (int ni=0; ni<4; ni++)
        acc[mi][ni] = __builtin_amdgcn_mfma_f32_16x16x32_bf16(af[mi], bfr[ni], acc[mi][ni], 0, 0, 0);
    __syncthreads();
  }

  // epilogue
  #pragma unroll
  for (int ni=0; ni<4; ni++){
    int col = n0 + wn*64 + ni*16 + l16;
    float bval = bz ? bz[col] : 0.f;
    #pragma unroll
    for (int mi=0; mi<4; mi++){
      int rbase = m_start + wm*64 + mi*16 + quad*4;
      floatx4 v = acc[mi][ni];
      #pragma unroll
      for (int r=0; r<4; r++){
        int grow = rbase + r;
        if (grow < m_end){
          float x = v[r] + bval;
          if (relu) x = fmaxf(x, 0.f);
          if (outBf16)
            ((unsigned short*)C)[(long long)z*strideCz + (long long)grow*N + col] = f2bf(x);
          else
            ((float*)C)[(long long)z*strideCz + (long long)grow*N + col] = x;
        }
      }
    }
  }
}

// ---------------- small-N row dot: out[(z*B+b)*NCOL+c] = h.W3 + b3 ----------------
template<int NCOL>
__global__ void k_rowdot(const unsigned short* __restrict__ H, const float* __restrict__ W3,
                         const float* __restrict__ b3, float* __restrict__ out, int Bn){
  int b = blockIdx.x, z = blockIdx.y, lane = threadIdx.x;
  const unsigned short* h = H + ((long long)z*Bn + b)*HID;
  const float* w = W3 + (long long)z*HID*NCOL;
  float acc[NCOL];
  #pragma unroll
  for (int c=0;c<NCOL;c++) acc[c]=0.f;
  for (int i = lane; i < HID; i += 64){
    float hv = bf2f(h[i]);
    #pragma unroll
    for (int c=0;c<NCOL;c++) acc[c] += hv * w[(long long)i*NCOL + c];
  }
  #pragma unroll
  for (int c=0;c<NCOL;c++)
    for (int o=32;o;o>>=1) acc[c] += __shfl_xor(acc[c], o);
  if (lane == 0){
    #pragma unroll
    for (int c=0;c<NCOL;c++) out[((long long)z*Bn + b)*NCOL + c] = acc[c] + b3[z*NCOL + c];
  }
}

// ---------------- beta head: sigmoid(hb . W2[o] + b2[o]) ----------------
__global__ void k_beta(const unsigned short* __restrict__ HB, const float* __restrict__ W2,
                       const float* __restrict__ b2, const int* __restrict__ perm,
                       const int* __restrict__ optg, float* __restrict__ outBeta,
                       float* __restrict__ bp){
  int i = blockIdx.x, lane = threadIdx.x;
  int o = optg[i], b = perm[i];
  const unsigned short* h = HB + (long long)i*HID;
  const float* w = W2 + (long long)o*HID;
  float acc = 0.f;
  for (int k = lane; k < HID; k += 64) acc += bf2f(h[k]) * w[k];
  for (int s=32;s;s>>=1) acc += __shfl_xor(acc, s);
  if (lane == 0){
    float v = 1.f/(1.f + expf(-(acc + b2[o])));
    outBeta[b] = v; bp[b] = v;
  }
}

// ---------------- policy epilogue: mu/ls -> pre, tanh, logp ----------------
__global__ void k_polep(const float* __restrict__ muls, const float* __restrict__ noise,
                        const float* __restrict__ bmu, const float* __restrict__ bls,
                        const int* __restrict__ perm, const int* __restrict__ optg,
                        float* __restrict__ out, float* __restrict__ logp_buf){
  int i = blockIdx.x; int a = threadIdx.x; // 64
  int o = optg[i], b = perm[i];
  float mu = muls[(long long)i*128 + a] + bmu[o*ACT + a];
  float ls = muls[(long long)i*128 + 64 + a] + bls[o*ACT + a];
  ls = fminf(fmaxf(ls, -20.f), 2.f);
  float nv = noise[(long long)b*ACT + a];
  float pre = mu + expf(ls)*nv;
  out[2 + (long long)b*ACT + a] = tanhf(pre);
  float xx = -2.f*pre;
  float sp = fmaxf(xx, 0.f) + log1pf(expf(-fabsf(xx)));
  const float LOG2PI = 1.8378770664093453f;
  const float LN2 = 0.6931471805599453f;
  float lp = -0.5f*nv*nv - ls - 0.5f*LOG2PI - 2.f*(LN2 - pre - sp);
  for (int s=32;s;s>>=1) lp += __shfl_xor(lp, s);
  if (a == 0){ out[2 + (long long)B_SZ*ACT + b] = lp; logp_buf[b] = lp; }
}

// ---------------- TD target + both losses ----------------
__global__ void k_td(const float* __restrict__ qi, const float* __restrict__ qon,
                     const float* __restrict__ qt, const int* __restrict__ option,
                     const float* __restrict__ reward, const float* __restrict__ done,
                     const float* __restrict__ bp, const float* __restrict__ logp_buf,
                     float* __restrict__ out){
  int b = blockIdx.x*256 + threadIdx.x;
  float qitv[NOPT];
  #pragma unroll
  for (int o=0;o<NOPT;o++)
    qitv[o] = fminf(qt[(long long)b*NOPT + o], qt[(long long)(B_SZ + b)*NOPT + o]);
  float qcur = qitv[option[b]];
  float best = -1e30f; int bo = 0;
  #pragma unroll
  for (int o=0;o<NOPT;o++){
    float v = fminf(qon[(long long)b*NOPT + o], qon[(long long)(B_SZ + b)*NOPT + o]);
    if (v > best){ best = v; bo = o; }
  }
  float qnext = qitv[bo];
  float bpv = bp[b];
  float backup = reward[b] + 0.99f*(1.f - done[b])*((1.f - bpv)*qcur + bpv*qnext);
  float d1 = qi[b] - backup, d2 = qi[B_SZ + b] - backup;
  float tq = d1*d1 + d2*d2;
  float qpi = fminf(qi[b], qi[B_SZ + b]);
  float tp = 0.2f*logp_buf[b] - qpi;
  for (int s=32;s;s>>=1){ tq += __shfl_xor(tq, s); tp += __shfl_xor(tp, s); }
  __shared__ float sq[4], sp2[4];
  int wave = threadIdx.x>>6, lane = threadIdx.x&63;
  if (lane==0){ sq[wave]=tq; sp2[wave]=tp; }
  __syncthreads();
  if (threadIdx.x==0){
    atomicAdd(&out[0], (sq[0]+sq[1]+sq[2]+sq[3])/(float)B_SZ);
    atomicAdd(&out[1], (sp2[0]+sp2[1]+sp2[2]+sp2[3])/(float)B_SZ);
  }
}

extern "C" void kernel_launch(void* const* d_in, const int* in_sizes, int n_in,
                              void* d_out, int out_size, void* d_ws, size_t ws_size,
                              hipStream_t stream){
  const float* state  = (const float*)d_in[0];
  const float* action = (const float*)d_in[1];
  const float* nstate = (const float*)d_in[2];
  const float* reward = (const float*)d_in[3];
  const float* done   = (const float*)d_in[4];
  const float* noise  = (const float*)d_in[5];
  const int*   option = (const int*)d_in[6];
  const float* iq_W1 = (const float*)d_in[7];  const float* iq_b1 = (const float*)d_in[8];
  const float* iq_W2 = (const float*)d_in[9];  const float* iq_b2 = (const float*)d_in[10];
  const float* iq_W3 = (const float*)d_in[11]; const float* iq_b3 = (const float*)d_in[12];
  const float* tq_W1 = (const float*)d_in[13]; const float* tq_b1 = (const float*)d_in[14];
  const float* tq_W2 = (const float*)d_in[15]; const float* tq_b2 = (const float*)d_in[16];
  const float* tq_W3 = (const float*)d_in[17]; const float* tq_b3 = (const float*)d_in[18];
  const float* xw_W1 = (const float*)d_in[19]; const float* xw_b1 = (const float*)d_in[20];
  const float* xw_W2 = (const float*)d_in[21]; const float* xw_b2 = (const float*)d_in[22];
  const float* xw_W3 = (const float*)d_in[23]; const float* xw_b3 = (const float*)d_in[24];
  const float* p_W1 = (const float*)d_in[25];  const float* p_b1 = (const float*)d_in[26];
  const float* p_W2 = (const float*)d_in[27];  const float* p_b2 = (const float*)d_in[28];
  const float* p_Wmu = (const float*)d_in[29]; const float* p_bmu = (const float*)d_in[30];
  const float* p_Wls = (const float*)d_in[31]; const float* p_bls = (const float*)d_in[32];
  const float* be_W1 = (const float*)d_in[33]; const float* be_b1 = (const float*)d_in[34];
  const float* be_W2 = (const float*)d_in[35]; const float* be_b2 = (const float*)d_in[36];
  float* out = (float*)d_out;

  char* ws = (char*)d_ws;
  size_t off = 0;
  auto alloc = [&](size_t bytes)->char*{
    char* p = ws + off; off += (bytes + 255) & ~(size_t)255; return p;
  };
  unsigned short* WT_x1 = (unsigned short*)alloc(2ll*HID*DPAD*2);
  unsigned short* WT_x2 = (unsigned short*)alloc(2ll*HID*HID*2);
  unsigned short* WT_i1 = (unsigned short*)alloc(2ll*HID*OBS*2);
  unsigned short* WT_i2 = (unsigned short*)alloc(2ll*HID*HID*2);
  unsigned short* WT_t1 = (unsigned short*)alloc(2ll*HID*OBS*2);
  unsigned short* WT_t2 = (unsigned short*)alloc(2ll*HID*HID*2);
  unsigned short* WT_p1 = (unsigned short*)alloc(8ll*HID*OBS*2);
  unsigned short* WT_p2 = (unsigned short*)alloc(8ll*HID*HID*2);
  unsigned short* WT_ml = (unsigned short*)alloc(8ll*128*HID*2);
  unsigned short* WT_b1 = (unsigned short*)alloc(8ll*HID*OBS*2);
  unsigned short* xqb   = (unsigned short*)alloc((long long)B_SZ*DPAD*2);
  unsigned short* nsb   = (unsigned short*)alloc((long long)B_SZ*OBS*2);
  unsigned short* agS   = (unsigned short*)alloc(4224ll*OBS*2);
  unsigned short* agN   = (unsigned short*)alloc(4224ll*OBS*2);
  unsigned short* hA    = (unsigned short*)alloc(2ll*B_SZ*HID*2);
  unsigned short* hB    = (unsigned short*)alloc(2ll*B_SZ*HID*2);
  float* muls = (float*)alloc(4224ll*128*4);
  float* qi   = (float*)alloc(2ll*B_SZ*4);
  float* qon  = (float*)alloc(2ll*B_SZ*NOPT*4);
  float* qt   = (float*)alloc(2ll*B_SZ*NOPT*4);
  int* perm   = (int*)alloc(B_SZ*4);
  int* optg   = (int*)alloc(4224*4);
  float* bp   = (float*)alloc(B_SZ*4);
  float* logp = (float*)alloc(B_SZ*4);
  int4* table = (int4*)alloc(MAXTILES*16);
  if (off > ws_size) return;  // workspace insufficient -> visible failure

  dim3 tb(32,8);
  // weight transposes (fp32 -> bf16 [N][Kpad])
  k_transpose<<<dim3(8,32,2), tb, 0, stream>>>(iq_W1, WT_i1, OBS, HID, OBS, (long long)OBS*HID, (long long)HID*OBS);
  k_transpose<<<dim3(32,32,2), tb, 0, stream>>>(iq_W2, WT_i2, HID, HID, HID, (long long)HID*HID, (long long)HID*HID);
  k_transpose<<<dim3(8,32,2), tb, 0, stream>>>(tq_W1, WT_t1, OBS, HID, OBS, (long long)OBS*HID, (long long)HID*OBS);
  k_transpose<<<dim3(32,32,2), tb, 0, stream>>>(tq_W2, WT_t2, HID, HID, HID, (long long)HID*HID, (long long)HID*HID);
  k_transpose<<<dim3(12,32,2), tb, 0, stream>>>(xw_W1, WT_x1, DIN, HID, DPAD, (long long)DIN*HID, (long long)HID*DPAD);
  k_transpose<<<dim3(32,32,2), tb, 0, stream>>>(xw_W2, WT_x2, HID, HID, HID, (long long)HID*HID, (long long)HID*HID);
  k_transpose<<<dim3(8,32,8), tb, 0, stream>>>(p_W1, WT_p1, OBS, HID, OBS, (long long)OBS*HID, (long long)HID*OBS);
  k_transpose<<<dim3(32,32,8), tb, 0, stream>>>(p_W2, WT_p2, HID, HID, HID, (long long)HID*HID, (long long)HID*HID);
  k_transpose<<<dim3(32,2,8), tb, 0, stream>>>(p_Wmu, WT_ml,            HID, ACT, HID, (long long)HID*ACT, 128ll*HID);
  k_transpose<<<dim3(32,2,8), tb, 0, stream>>>(p_Wls, WT_ml + 64*HID,   HID, ACT, HID, (long long)HID*ACT, 128ll*HID);
  k_transpose<<<dim3(8,32,8), tb, 0, stream>>>(be_W1, WT_b1, OBS, HID, OBS, (long long)OBS*HID, (long long)HID*OBS);

  // routing + input prep
  k_route<<<1, 256, 0, stream>>>(option, perm, optg, table, out);
  k_gather<<<4224, 256, 0, stream>>>(state, nstate, perm, agS, agN);
  k_xq<<<B_SZ, DPAD, 0, stream>>>(state, action, option, xqb);
  k_cvt<<<(B_SZ*OBS)/256, 256, 0, stream>>>(nstate, nsb, (long long)B_SZ*OBS);

  long long sBH = (long long)B_SZ*HID;
  // intra-Q: xq -> h1 -> h2 -> q (z=2)
  k_gemm<<<dim3(8,32,2), 256, 0, stream>>>(xqb, 0, WT_x1, (long long)HID*DPAD, xw_b1, HID, hA, sBH, B_SZ, HID, DPAD, 1, 1, nullptr);
  k_gemm<<<dim3(8,32,2), 256, 0, stream>>>(hA, sBH, WT_x2, (long long)HID*HID, xw_b2, HID, hB, sBH, B_SZ, HID, HID, 1, 1, nullptr);
  k_rowdot<1><<<dim3(B_SZ,2), 64, 0, stream>>>(hB, xw_W3, xw_b3, qi, B_SZ);
  // online inter-Q on next_state
  k_gemm<<<dim3(8,32,2), 256, 0, stream>>>(nsb, 0, WT_i1, (long long)HID*OBS, iq_b1, HID, hA, sBH, B_SZ, HID, OBS, 1, 1, nullptr);
  k_gemm<<<dim3(8,32,2), 256, 0, stream>>>(hA, sBH, WT_i2, (long long)HID*HID, iq_b2, HID, hB, sBH, B_SZ, HID, HID, 1, 1, nullptr);
  k_rowdot<8><<<dim3(B_SZ,2), 64, 0, stream>>>(hB, iq_W3, iq_b3, qon, B_SZ);
  // target inter-Q on next_state
  k_gemm<<<dim3(8,32,2), 256, 0, stream>>>(nsb, 0, WT_t1, (long long)HID*OBS, tq_b1, HID, hA, sBH, B_SZ, HID, OBS, 1, 1, nullptr);
  k_gemm<<<dim3(8,32,2), 256, 0, stream>>>(hA, sBH, WT_t2, (long long)HID*HID, tq_b2, HID, hB, sBH, B_SZ, HID, HID, 1, 1, nullptr);
  k_rowdot<8><<<dim3(B_SZ,2), 64, 0, stream>>>(hB, tq_W3, tq_b3, qt, B_SZ);
  // grouped policy (routed by option)
  k_gemm<<<dim3(8,MAXTILES,1), 256, 0, stream>>>(agS, 0, WT_p1, (long long)HID*OBS, p_b1, HID, hA, 0, B_SZ, HID, OBS, 1, 1, table);
  k_gemm<<<dim3(8,MAXTILES,1), 256, 0, stream>>>(hA, 0, WT_p2, (long long)HID*HID, p_b2, HID, hB, 0, B_SZ, HID, HID, 1, 1, table);
  k_gemm<<<dim3(1,MAXTILES,1), 256, 0, stream>>>(hB, 0, WT_ml, 128ll*HID, nullptr, 0, muls, 0, B_SZ, 128, HID, 0, 0, table);
  // grouped beta net on next_state
  k_gemm<<<dim3(8,MAXTILES,1), 256, 0, stream>>>(agN, 0, WT_b1, (long long)HID*OBS, be_b1, HID, hA, 0, B_SZ, HID, OBS, 1, 1, table);
  k_beta<<<B_SZ, 64, 0, stream>>>(hA, be_W2, be_b2, perm, optg, out + 2 + (long long)B_SZ*ACT + B_SZ, bp);
  // policy epilogue + TD/losses
  k_polep<<<B_SZ, 64, 0, stream>>>(muls, noise, p_bmu, p_bls, perm, optg, out, logp);
  k_td<<<B_SZ/256, 256, 0, stream>>>(qi, qon, qt, option, reward, done, bp, logp, out);
}